// Round 2
// baseline (914.353 us; speedup 1.0000x reference)
//
#include <hip/hip_runtime.h>

#define ROWS 131072
#define DD   256
#define MM   512
#define CH   264   // bf16 stride per 8-col chunk: 528B = 33*16B (16B-aligned, banks vary by 4/row)

typedef __attribute__((ext_vector_type(8))) short v8s;
typedef __attribute__((ext_vector_type(4))) float v4f;

static __device__ __forceinline__ unsigned short f2bf(float f) {
  union { float f; unsigned int u; } c; c.f = f;
  unsigned int u = c.u;
  return (unsigned short)((u + 0x7fffu + ((u >> 16) & 1u)) >> 16);  // RNE
}
static __device__ __forceinline__ float bf2f(unsigned short h) {
  union { float f; unsigned int u; } c; c.u = ((unsigned int)h) << 16;
  return c.f;
}
// chunked-K LDS offset: col in [0,256), row in [0,32)
static __device__ __forceinline__ int ld_off(int col, int row) {
  return (col >> 3) * CH + row * 8 + (col & 7);
}

__global__ void vm_prep(const float* __restrict__ mem, const float* __restrict__ Wg,
                        unsigned short* __restrict__ mh, unsigned short* __restrict__ ml,
                        unsigned short* __restrict__ mT, unsigned short* __restrict__ W1b,
                        unsigned short* __restrict__ W2b) {
  int i = blockIdx.x * 256 + threadIdx.x;  // 0..131071
  float v = mem[i];
  unsigned short h = f2bf(v);
  mh[i] = h;
  ml[i] = f2bf(v - bf2f(h));
  int m = i >> 8, d = i & 255;
  mT[d * MM + m] = h;
  float wv = Wg[i];
  int e = i >> 9, c = i & 511;
  unsigned short wb = f2bf(wv);
  if (c < DD) W1b[e * DD + c] = wb;
  else        W2b[e * DD + (c - DD)] = wb;
}

// 32 rows/block, 4 waves. GEMM1: wave w owns sim cols [w*128, w*128+128).
// GEMM2/3: wave w owns d/e cols [w*64, w*64+64).
__global__ __launch_bounds__(256, 3) void vm_main(
    const float* __restrict__ x, const float* __restrict__ bg,
    const unsigned short* __restrict__ mh, const unsigned short* __restrict__ ml,
    const unsigned short* __restrict__ mT, const unsigned short* __restrict__ W1b,
    const unsigned short* __restrict__ W2b,
    float* __restrict__ out_e, float* __restrict__ out_w)
{
  __shared__ __align__(16) unsigned short sm_xh[32 * CH];  // x hi, lives whole kernel
  __shared__ __align__(16) unsigned short sm_b[32 * CH];   // x lo -> P-half -> mr -> enhanced
  __shared__ float sm_rmax[32 * 4];
  __shared__ float sm_rsum[32 * 4];

  const int tid  = threadIdx.x;
  const int w    = tid >> 6;
  const int lane = tid & 63;
  const int q    = lane >> 4;
  const int n    = lane & 15;
  const long R0  = (long)blockIdx.x * 32;

  // ---- stage x rows R0..R0+31 as bf16 hi/lo, chunked layout ----
  {
    const int r = tid >> 3, k = tid & 7;
    const float* xr = x + (R0 + r) * (long)DD;
#pragma unroll
    for (int j = 0; j < 8; ++j) {
      const int col = k * 4 + j * 32;
      float4 v = *(const float4*)(xr + col);
      float vv[4] = {v.x, v.y, v.z, v.w};
      unsigned int hh[4], ll[4];
#pragma unroll
      for (int i = 0; i < 4; ++i) {
        unsigned short h = f2bf(vv[i]);
        hh[i] = h;
        ll[i] = f2bf(vv[i] - bf2f(h));
      }
      uint2 hv = make_uint2(hh[0] | (hh[1] << 16), hh[2] | (hh[3] << 16));
      uint2 lv = make_uint2(ll[0] | (ll[1] << 16), ll[2] | (ll[3] << 16));
      const int off = (col >> 3) * CH + r * 8 + (col & 7);  // (col&7) in {0,4}
      *(uint2*)&sm_xh[off] = hv;
      *(uint2*)&sm_b[off]  = lv;
    }
  }
  __syncthreads();

  // ---- GEMM1: sim[32 x 128(cols of wave)] = x . mem^T, 3-term bf16 split ----
  v4f acc1[2][8];
#pragma unroll
  for (int mt = 0; mt < 2; ++mt)
#pragma unroll
    for (int nt = 0; nt < 8; ++nt) { acc1[mt][nt][0]=0.f; acc1[mt][nt][1]=0.f; acc1[mt][nt][2]=0.f; acc1[mt][nt][3]=0.f; }

  for (int ki = 0; ki < 8; ++ki) {
    const int cb = (ki * 4 + q) * CH;
    v8s ah[2], al[2];
#pragma unroll
    for (int mt = 0; mt < 2; ++mt) {
      ah[mt] = *(const v8s*)&sm_xh[cb + (mt * 16 + n) * 8];
      al[mt] = *(const v8s*)&sm_b [cb + (mt * 16 + n) * 8];
    }
#pragma unroll
    for (int nt = 0; nt < 8; ++nt) {
      const int mrow = w * 128 + nt * 16 + n;
      const int gc = mrow * DD + ki * 32 + q * 8;
      v8s bh = *(const v8s*)(mh + gc);
      v8s bl = *(const v8s*)(ml + gc);
#pragma unroll
      for (int mt = 0; mt < 2; ++mt) {
        acc1[mt][nt] = __builtin_amdgcn_mfma_f32_16x16x32_bf16(ah[mt], bh, acc1[mt][nt], 0, 0, 0);
        acc1[mt][nt] = __builtin_amdgcn_mfma_f32_16x16x32_bf16(al[mt], bh, acc1[mt][nt], 0, 0, 0);
        acc1[mt][nt] = __builtin_amdgcn_mfma_f32_16x16x32_bf16(ah[mt], bl, acc1[mt][nt], 0, 0, 0);
      }
    }
  }

  // ---- softmax over M=512: wave-partial -> shuffle(n) -> LDS cross-wave ----
  // C layout: row = mt*16 + q*4 + reg, col = w*128 + nt*16 + n
  float rmax[2][4];
#pragma unroll
  for (int mt = 0; mt < 2; ++mt)
#pragma unroll
    for (int reg = 0; reg < 4; ++reg) {
      float mv = acc1[mt][0][reg];
#pragma unroll
      for (int nt = 1; nt < 8; ++nt) mv = fmaxf(mv, acc1[mt][nt][reg]);
      rmax[mt][reg] = mv;
    }
#pragma unroll
  for (int off = 1; off < 16; off <<= 1)
#pragma unroll
    for (int mt = 0; mt < 2; ++mt)
#pragma unroll
      for (int reg = 0; reg < 4; ++reg)
        rmax[mt][reg] = fmaxf(rmax[mt][reg], __shfl_xor(rmax[mt][reg], off, 64));
  if (n == 0) {
#pragma unroll
    for (int mt = 0; mt < 2; ++mt)
#pragma unroll
      for (int reg = 0; reg < 4; ++reg)
        sm_rmax[(mt * 16 + q * 4 + reg) * 4 + w] = rmax[mt][reg];
  }
  __syncthreads();
  float gmax[2][4];
#pragma unroll
  for (int mt = 0; mt < 2; ++mt)
#pragma unroll
    for (int reg = 0; reg < 4; ++reg) {
      v4f r4 = *(const v4f*)&sm_rmax[(mt * 16 + q * 4 + reg) * 4];
      gmax[mt][reg] = fmaxf(fmaxf(r4[0], r4[1]), fmaxf(r4[2], r4[3]));
    }
  float rsum[2][4];
#pragma unroll
  for (int mt = 0; mt < 2; ++mt)
#pragma unroll
    for (int reg = 0; reg < 4; ++reg) rsum[mt][reg] = 0.f;
#pragma unroll
  for (int mt = 0; mt < 2; ++mt)
#pragma unroll
    for (int nt = 0; nt < 8; ++nt)
#pragma unroll
      for (int reg = 0; reg < 4; ++reg) {
        float p = __expf(acc1[mt][nt][reg] - gmax[mt][reg]);
        acc1[mt][nt][reg] = p;
        rsum[mt][reg] += p;
      }
#pragma unroll
  for (int off = 1; off < 16; off <<= 1)
#pragma unroll
    for (int mt = 0; mt < 2; ++mt)
#pragma unroll
      for (int reg = 0; reg < 4; ++reg)
        rsum[mt][reg] += __shfl_xor(rsum[mt][reg], off, 64);
  if (n == 0) {
#pragma unroll
    for (int mt = 0; mt < 2; ++mt)
#pragma unroll
      for (int reg = 0; reg < 4; ++reg)
        sm_rsum[(mt * 16 + q * 4 + reg) * 4 + w] = rsum[mt][reg];
  }
  __syncthreads();

  // normalize -> pack P to bf16 pairs in regs (32 VGPRs); weights hit HBM via LDS readback later
  unsigned int pk[2][4][4];
#pragma unroll
  for (int mt = 0; mt < 2; ++mt)
#pragma unroll
    for (int reg = 0; reg < 4; ++reg) {
      v4f s4 = *(const v4f*)&sm_rsum[(mt * 16 + q * 4 + reg) * 4];
      const float ginv = 1.0f / (s4[0] + s4[1] + s4[2] + s4[3]);
#pragma unroll
      for (int nt = 0; nt < 8; ++nt) {
        unsigned int u = f2bf(acc1[mt][nt][reg] * ginv);
        if (nt & 1) pk[mt][nt >> 1][reg] |= (u << 16);
        else        pk[mt][nt >> 1][reg]  = u;
      }
    }
  __syncthreads();  // sm_b (x-lo) now dead; reuse for P halves

  // ---- GEMM2: mr[32 x 64(d of wave)] = P . mem, K=512 in two 256-halves via LDS ----
  v4f acc2[2][4];
#pragma unroll
  for (int mt = 0; mt < 2; ++mt)
#pragma unroll
    for (int nt = 0; nt < 4; ++nt) { acc2[mt][nt][0]=0.f; acc2[mt][nt][1]=0.f; acc2[mt][nt][2]=0.f; acc2[mt][nt][3]=0.f; }

  for (int kh = 0; kh < 2; ++kh) {
    if ((w >> 1) == kh) {   // waves owning these 256 sim-cols stage their P slice
      const int cb = (w & 1) * 128;
#pragma unroll
      for (int mt = 0; mt < 2; ++mt)
#pragma unroll
        for (int ntp = 0; ntp < 4; ++ntp)
#pragma unroll
          for (int reg = 0; reg < 4; ++reg) {
            const int r = mt * 16 + q * 4 + reg;
            const unsigned int u = pk[mt][ntp][reg];
            const int c0 = cb + (2 * ntp) * 16 + n;
            sm_b[ld_off(c0,      r)] = (unsigned short)(u & 0xffffu);
            sm_b[ld_off(c0 + 16, r)] = (unsigned short)(u >> 16);
          }
    }
    __syncthreads();
    for (int ki = 0; ki < 8; ++ki) {
      const int cb = (ki * 4 + q) * CH;
      v8s pa[2];
#pragma unroll
      for (int mt = 0; mt < 2; ++mt)
        pa[mt] = *(const v8s*)&sm_b[cb + (mt * 16 + n) * 8];
#pragma unroll
      for (int nt = 0; nt < 4; ++nt) {
        const int dcol = w * 64 + nt * 16 + n;
        v8s bt = *(const v8s*)(mT + dcol * MM + kh * 256 + ki * 32 + q * 8);
#pragma unroll
        for (int mt = 0; mt < 2; ++mt)
          acc2[mt][nt] = __builtin_amdgcn_mfma_f32_16x16x32_bf16(pa[mt], bt, acc2[mt][nt], 0, 0, 0);
      }
    }
    // cooperative coalesced out_w write for this 256-col half (reads sm_b only)
    {
      const int r = tid >> 3, k = tid & 7;
      float* wr = out_w + (R0 + r) * (long)MM + kh * 256;
#pragma unroll
      for (int j = 0; j < 8; ++j) {
        const int col = k * 4 + j * 32;
        uint2 pv = *(const uint2*)&sm_b[(col >> 3) * CH + r * 8 + (col & 7)];
        float4 o = make_float4(bf2f((unsigned short)(pv.x & 0xffffu)),
                               bf2f((unsigned short)(pv.x >> 16)),
                               bf2f((unsigned short)(pv.y & 0xffffu)),
                               bf2f((unsigned short)(pv.y >> 16)));
        *(float4*)(wr + col) = o;
      }
    }
    __syncthreads();
  }

  // ---- stage mr (bf16) for GEMM3 A-operand ----
#pragma unroll
  for (int mt = 0; mt < 2; ++mt)
#pragma unroll
    for (int nt = 0; nt < 4; ++nt)
#pragma unroll
      for (int reg = 0; reg < 4; ++reg) {
        const int r = mt * 16 + q * 4 + reg;
        const int col = w * 64 + nt * 16 + n;
        sm_b[ld_off(col, r)] = f2bf(acc2[mt][nt][reg]);
      }
  __syncthreads();

  // ---- GEMM3: gate logits = x.W1^T + mr.W2^T over e-cols of wave ----
  v4f acc3[2][4];
#pragma unroll
  for (int mt = 0; mt < 2; ++mt)
#pragma unroll
    for (int nt = 0; nt < 4; ++nt) { acc3[mt][nt][0]=0.f; acc3[mt][nt][1]=0.f; acc3[mt][nt][2]=0.f; acc3[mt][nt][3]=0.f; }

  for (int ki = 0; ki < 8; ++ki) {
    const int cb = (ki * 4 + q) * CH;
    v8s xa[2], ma[2];
#pragma unroll
    for (int mt = 0; mt < 2; ++mt) {
      xa[mt] = *(const v8s*)&sm_xh[cb + (mt * 16 + n) * 8];
      ma[mt] = *(const v8s*)&sm_b [cb + (mt * 16 + n) * 8];
    }
#pragma unroll
    for (int nt = 0; nt < 4; ++nt) {
      const int e = w * 64 + nt * 16 + n;
      v8s b1 = *(const v8s*)(W1b + e * DD + ki * 32 + q * 8);
      v8s b2 = *(const v8s*)(W2b + e * DD + ki * 32 + q * 8);
#pragma unroll
      for (int mt = 0; mt < 2; ++mt) {
        acc3[mt][nt] = __builtin_amdgcn_mfma_f32_16x16x32_bf16(xa[mt], b1, acc3[mt][nt], 0, 0, 0);
        acc3[mt][nt] = __builtin_amdgcn_mfma_f32_16x16x32_bf16(ma[mt], b2, acc3[mt][nt], 0, 0, 0);
      }
    }
  }
  __syncthreads();  // sm_b (mr) consumed; reuse for enhanced

  // ---- epilogue: enhanced = x + sigmoid(logit + bg) * mr, staged bf16 ----
#pragma unroll
  for (int nt = 0; nt < 4; ++nt) {
    const int col = w * 64 + nt * 16 + n;
    const float bgv = bg[col];
#pragma unroll
    for (int mt = 0; mt < 2; ++mt)
#pragma unroll
      for (int reg = 0; reg < 4; ++reg) {
        const int r = mt * 16 + q * 4 + reg;
        float z = acc3[mt][nt][reg] + bgv;
        float g = 1.0f / (1.0f + __expf(-z));
        float xv = bf2f(sm_xh[ld_off(col, r)]);
        sm_b[ld_off(col, r)] = f2bf(xv + g * acc2[mt][nt][reg]);
      }
  }
  __syncthreads();
  {
    const int r = tid >> 3, k = tid & 7;
    float* er = out_e + (R0 + r) * (long)DD;
#pragma unroll
    for (int j = 0; j < 8; ++j) {
      const int col = k * 4 + j * 32;
      uint2 pv = *(const uint2*)&sm_b[(col >> 3) * CH + r * 8 + (col & 7)];
      float4 o = make_float4(bf2f((unsigned short)(pv.x & 0xffffu)),
                             bf2f((unsigned short)(pv.x >> 16)),
                             bf2f((unsigned short)(pv.y & 0xffffu)),
                             bf2f((unsigned short)(pv.y >> 16)));
      *(float4*)(er + col) = o;
    }
  }
}

extern "C" void kernel_launch(void* const* d_in, const int* in_sizes, int n_in,
                              void* d_out, int out_size, void* d_ws, size_t ws_size,
                              hipStream_t stream) {
  const float* x   = (const float*)d_in[0];
  const float* mem = (const float*)d_in[1];
  const float* Wg  = (const float*)d_in[2];
  const float* bg  = (const float*)d_in[3];

  unsigned short* mh  = (unsigned short*)d_ws;          // 512*256
  unsigned short* ml  = mh  + 131072;                   // 512*256
  unsigned short* mT  = ml  + 131072;                   // 256*512
  unsigned short* W1b = mT  + 131072;                   // 256*256
  unsigned short* W2b = W1b + 65536;                    // 256*256  (total ws: 1 MiB)

  float* out_e = (float*)d_out;                         // (32,4096,256)
  float* out_w = out_e + (long)ROWS * DD;               // (32,4096,512)

  vm_prep<<<512, 256, 0, stream>>>(mem, Wg, mh, ml, mT, W1b, W2b);
  vm_main<<<4096, 256, 0, stream>>>(x, bg, mh, ml, mT, W1b, W2b, out_e, out_w);
}